// Round 1
// baseline (972.906 us; speedup 1.0000x reference)
//
#include <hip/hip_runtime.h>
#include <hip/hip_bf16.h>

typedef __hip_bfloat16 bf16;
typedef __bf16 bf16x8 __attribute__((ext_vector_type(8)));
typedef float f32x4 __attribute__((ext_vector_type(4)));

#define N_TOK 131072
#define C_DIM 256
#define HID_DIM 1024

// async global->LDS, 16B per lane; lds base must be wave-uniform (dest = base + lane*16)
__device__ __forceinline__ void async_copy16(void* lds, const void* g) {
  __builtin_amdgcn_global_load_lds(
      (const __attribute__((address_space(1))) void*)g,
      (__attribute__((address_space(3))) void*)lds, 16, 0, 0);
}

// JAX default gelu (approximate=True, tanh form); tanh(y) = 1 - 2/(e^{2y}+1), inf-safe
__device__ __forceinline__ float fast_gelu(float x) {
  float y = 0.7978845608028654f * (x + 0.044715f * x * x * x);
  float e = __expf(2.f * y);
  float th = 1.f - 2.f / (e + 1.f);
  return 0.5f * x * (1.f + th);
}

// LayerNorm over C=256, fp32 in -> bf16 out. block (64,4): one wave per row.
__global__ void ln_bf16_kernel(const float* __restrict__ x,
                               const float* __restrict__ g,
                               const float* __restrict__ b,
                               bf16* __restrict__ out) {
  int row = blockIdx.x * 4 + threadIdx.y;
  int lane = threadIdx.x;
  size_t base = (size_t)row * C_DIM + lane * 4;
  float4 v = *(const float4*)(x + base);
  float s = v.x + v.y + v.z + v.w;
  float s2 = v.x * v.x + v.y * v.y + v.z * v.z + v.w * v.w;
#pragma unroll
  for (int m = 1; m < 64; m <<= 1) { s += __shfl_xor(s, m); s2 += __shfl_xor(s2, m); }
  float mean = s * (1.f / 256.f);
  float var = s2 * (1.f / 256.f) - mean * mean;
  float rstd = rsqrtf(var + 1e-5f);
  float4 gv = *(const float4*)(g + lane * 4);
  float4 bv = *(const float4*)(b + lane * 4);
  union { bf16 h[4]; uint2 u; } pk;
  pk.h[0] = __float2bfloat16((v.x - mean) * rstd * gv.x + bv.x);
  pk.h[1] = __float2bfloat16((v.y - mean) * rstd * gv.y + bv.y);
  pk.h[2] = __float2bfloat16((v.z - mean) * rstd * gv.z + bv.z);
  pk.h[3] = __float2bfloat16((v.w - mean) * rstd * gv.w + bv.w);
  *(uint2*)(out + base) = pk.u;
}

// weight [K,N] fp32 -> [N,K] bf16 (transposed so GEMM reads are K-contiguous)
__global__ void cast_transpose_kernel(const float* __restrict__ in, bf16* __restrict__ out,
                                      int K, int N) {
  int idx = blockIdx.x * 256 + threadIdx.x;
  if (idx >= K * N) return;
  int n = idx / K, k = idx - n * K;
  out[idx] = __float2bfloat16(in[(size_t)k * N + n]);
}

// C[m,n] = sum_k A[m,k]*Bt[n,k] + bias[n] (+ epilogue). 128x128 tile, BK=64,
// 256 thr = 4 waves each 64x64 (4x4 of 16x16x32 MFMA). m97-style global_load_lds staging.
// EPI: 0 = bf16 out; 1 = fp32 out + res; 2 = gelu -> bf16; 3 = fp32 out + res
template <int EPI>
__global__ __launch_bounds__(256) void gemm_bt_kernel(
    const bf16* __restrict__ A, const bf16* __restrict__ Bt,
    const float* __restrict__ bias, const float* __restrict__ res,
    void* __restrict__ outp, int K, int ldn) {
  __shared__ bf16 sA[128 * 64];
  __shared__ bf16 sB[128 * 64];
  const int tid = threadIdx.x;
  const int wid = tid >> 6;
  const int lane = tid & 63;
  const int quad = lane >> 4;
  const int l16 = lane & 15;
  const int m0 = blockIdx.x * 128;
  const int n0 = blockIdx.y * 128;
  const int wm = (wid >> 1) * 64;
  const int wn = (wid & 1) * 64;
  const int srow = tid >> 3;        // staging row within 32-row issue slab
  const int scol = (tid & 7) * 8;   // staging col (8 bf16 = 16B)

  f32x4 acc[4][4] = {};

  for (int k0 = 0; k0 < K; k0 += 64) {
#pragma unroll
    for (int is = 0; is < 4; ++is) {
      async_copy16(&sA[is * 2048 + wid * 512],
                   &A[(size_t)(m0 + is * 32 + srow) * K + k0 + scol]);
      async_copy16(&sB[is * 2048 + wid * 512],
                   &Bt[(size_t)(n0 + is * 32 + srow) * K + k0 + scol]);
    }
    __syncthreads();  // drains vmcnt: staged tiles visible
#pragma unroll
    for (int kk = 0; kk < 64; kk += 32) {
      bf16x8 af[4], bfr[4];
#pragma unroll
      for (int i = 0; i < 4; ++i)
        af[i] = *(const bf16x8*)&sA[(wm + i * 16 + l16) * 64 + kk + quad * 8];
#pragma unroll
      for (int j = 0; j < 4; ++j)
        bfr[j] = *(const bf16x8*)&sB[(wn + j * 16 + l16) * 64 + kk + quad * 8];
#pragma unroll
      for (int i = 0; i < 4; ++i)
#pragma unroll
        for (int j = 0; j < 4; ++j)
          acc[i][j] = __builtin_amdgcn_mfma_f32_16x16x32_bf16(af[i], bfr[j], acc[i][j], 0, 0, 0);
    }
    __syncthreads();  // protect LDS before next staging
  }

#pragma unroll
  for (int i = 0; i < 4; ++i) {
    int rowb = m0 + wm + i * 16 + quad * 4;  // C/D layout: row = quad*4+reg
#pragma unroll
    for (int j = 0; j < 4; ++j) {
      int col = n0 + wn + j * 16 + l16;      // col = lane&15
      float bv = bias[col];
#pragma unroll
      for (int r = 0; r < 4; ++r) {
        size_t idx = (size_t)(rowb + r) * ldn + col;
        float v = acc[i][j][r] + bv;
        if constexpr (EPI == 0) {
          ((bf16*)outp)[idx] = __float2bfloat16(v);
        } else if constexpr (EPI == 1) {
          ((float*)outp)[idx] = v + res[idx];
        } else if constexpr (EPI == 2) {
          ((bf16*)outp)[idx] = __float2bfloat16(fast_gelu(v));
        } else {
          ((float*)outp)[idx] = v + res[idx];
        }
      }
    }
  }
}

// one block per (window p, head h): softmax(QK^T * scale) V with gather/scatter via order.
// qkv row layout: [0,256)=q, [256,512)=k, [512,768)=v, head h at h*32.
__global__ __launch_bounds__(256) void attn_kernel(
    const bf16* __restrict__ qkv, const int* __restrict__ order,
    bf16* __restrict__ outw) {
  __shared__ bf16 sK[128 * 40];    // K rows, +8 pad -> 2-way-max bank aliasing
  __shared__ bf16 sVt[32 * 136];   // V transposed [d][k], +8 pad
  __shared__ bf16 sP[128 * 136];   // softmax probs, +8 pad
  __shared__ int sOrd[128];
  const int p = blockIdx.x;
  const int h = blockIdx.y;
  const int tid = threadIdx.x;
  const int wid = tid >> 6;
  const int lane = tid & 63;
  const int quad = lane >> 4;
  const int l16 = lane & 15;

  if (tid < 128) sOrd[tid] = order[p * 128 + tid];
  __syncthreads();

  {  // stage K rows and V^T
    int r = tid >> 1;
    int half = (tid & 1) * 16;
    size_t base = (size_t)sOrd[r] * 768 + h * 32;
    uint4 ka = *(const uint4*)&qkv[base + 256 + half];
    uint4 kb = *(const uint4*)&qkv[base + 256 + half + 8];
    *(uint4*)&sK[r * 40 + half] = ka;
    *(uint4*)&sK[r * 40 + half + 8] = kb;
    union { uint4 u[2]; bf16 e[16]; } vv;
    vv.u[0] = *(const uint4*)&qkv[base + 512 + half];
    vv.u[1] = *(const uint4*)&qkv[base + 512 + half + 8];
#pragma unroll
    for (int c = 0; c < 16; ++c) sVt[(half + c) * 136 + r] = vv.e[c];
  }
  __syncthreads();

  // Q fragments straight from global: A-frag = Q[m = l16][k = quad*8+j], D=32 = one K-step
  bf16x8 qf[2];
#pragma unroll
  for (int t = 0; t < 2; ++t) {
    int r = wid * 32 + t * 16 + l16;
    qf[t] = *(const bf16x8*)&qkv[(size_t)sOrd[r] * 768 + h * 32 + quad * 8];
  }

  const f32x4 zero = {0.f, 0.f, 0.f, 0.f};
  f32x4 s[2][8];  // wave owns 32 q-rows x 128 keys
#pragma unroll
  for (int ct = 0; ct < 8; ++ct) {
    bf16x8 kf = *(const bf16x8*)&sK[(ct * 16 + l16) * 40 + quad * 8];  // B[k=d][n=key]
#pragma unroll
    for (int t = 0; t < 2; ++t)
      s[t][ct] = __builtin_amdgcn_mfma_f32_16x16x32_bf16(qf[t], kf, zero, 0, 0, 0);
  }

  const float scale = 0.17677669529663687f;  // 1/sqrt(32)
#pragma unroll
  for (int t = 0; t < 2; ++t) {
#pragma unroll
    for (int r = 0; r < 4; ++r) {  // row = wid*32 + t*16 + quad*4 + r, cols in 16-lane quad
      float mx = -1e30f;
#pragma unroll
      for (int ct = 0; ct < 8; ++ct) mx = fmaxf(mx, s[t][ct][r]);
      mx *= scale;
#pragma unroll
      for (int mk = 1; mk < 16; mk <<= 1) mx = fmaxf(mx, __shfl_xor(mx, mk));
      float sum = 0.f;
#pragma unroll
      for (int ct = 0; ct < 8; ++ct) {
        float e = __expf(scale * s[t][ct][r] - mx);
        s[t][ct][r] = e;
        sum += e;
      }
#pragma unroll
      for (int mk = 1; mk < 16; mk <<= 1) sum += __shfl_xor(sum, mk);
      float inv = 1.f / sum;
      int prow = wid * 32 + t * 16 + quad * 4 + r;
#pragma unroll
      for (int ct = 0; ct < 8; ++ct)
        sP[prow * 136 + ct * 16 + l16] = __float2bfloat16(s[t][ct][r] * inv);
    }
  }
  __syncthreads();  // P C-layout -> A-layout round trip through LDS

  f32x4 o[2][2] = {};
#pragma unroll
  for (int ks = 0; ks < 4; ++ks) {
    bf16x8 vf[2];
#pragma unroll
    for (int n = 0; n < 2; ++n)  // B[k][n=d]: read V^T[d][k] contiguously
      vf[n] = *(const bf16x8*)&sVt[(n * 16 + l16) * 136 + ks * 32 + quad * 8];
#pragma unroll
    for (int t = 0; t < 2; ++t) {
      bf16x8 pf = *(const bf16x8*)&sP[(wid * 32 + t * 16 + l16) * 136 + ks * 32 + quad * 8];
#pragma unroll
      for (int n = 0; n < 2; ++n)
        o[t][n] = __builtin_amdgcn_mfma_f32_16x16x32_bf16(pf, vf[n], o[t][n], 0, 0, 0);
    }
  }

#pragma unroll
  for (int t = 0; t < 2; ++t) {
    int rowb = wid * 32 + t * 16 + quad * 4;
#pragma unroll
    for (int r = 0; r < 4; ++r) {
      size_t gbase = (size_t)sOrd[rowb + r] * 256 + h * 32;  // scatter == out[inverse]
#pragma unroll
      for (int n = 0; n < 2; ++n)
        outw[gbase + n * 16 + l16] = __float2bfloat16(o[t][n][r]);
    }
  }
}

extern "C" void kernel_launch(void* const* d_in, const int* in_sizes, int n_in,
                              void* d_out, int out_size, void* d_ws, size_t ws_size,
                              hipStream_t stream) {
  const float* feat   = (const float*)d_in[0];
  const float* ln1_g  = (const float*)d_in[1];
  const float* ln1_b  = (const float*)d_in[2];
  const float* w_qkv  = (const float*)d_in[3];
  const float* b_qkv  = (const float*)d_in[4];
  const float* w_proj = (const float*)d_in[5];
  const float* b_proj = (const float*)d_in[6];
  const float* ln2_g  = (const float*)d_in[7];
  const float* ln2_b  = (const float*)d_in[8];
  const float* w1     = (const float*)d_in[9];
  const float* b1     = (const float*)d_in[10];
  const float* w2     = (const float*)d_in[11];
  const float* b2     = (const float*)d_in[12];
  const int* order    = (const int*)d_in[13];
  float* out = (float*)d_out;

  char* ws = (char*)d_ws;
  size_t off = 0;
  auto take = [&](size_t bytes) {
    char* pp = ws + off;
    off += (bytes + 255) & ~(size_t)255;
    return pp;
  };
  bf16* ln_buf  = (bf16*)take((size_t)N_TOK * 256 * 2);   // ln1, later reused for ln2
  bf16* qkv     = (bf16*)take((size_t)N_TOK * 768 * 2);
  bf16* attn_o  = (bf16*)take((size_t)N_TOK * 256 * 2);
  float* xres   = (float*)take((size_t)N_TOK * 256 * 4);
  bf16* wqkvT   = (bf16*)take(768 * 256 * 2);
  bf16* wprojT  = (bf16*)take(256 * 256 * 2);
  bf16* w1T     = (bf16*)take(1024 * 256 * 2);
  bf16* w2T     = (bf16*)take(256 * 1024 * 2);
  bf16* hbuf    = qkv;  // h (N*1024*2 B) exactly overlays dead qkv+attn_o region

  cast_transpose_kernel<<<768, 256, 0, stream>>>(w_qkv, wqkvT, 256, 768);
  cast_transpose_kernel<<<256, 256, 0, stream>>>(w_proj, wprojT, 256, 256);
  cast_transpose_kernel<<<1024, 256, 0, stream>>>(w1, w1T, 256, 1024);
  cast_transpose_kernel<<<1024, 256, 0, stream>>>(w2, w2T, 1024, 256);

  ln_bf16_kernel<<<N_TOK / 4, dim3(64, 4), 0, stream>>>(feat, ln1_g, ln1_b, ln_buf);
  gemm_bt_kernel<0><<<dim3(1024, 6), 256, 0, stream>>>(ln_buf, wqkvT, b_qkv, nullptr, qkv, 256, 768);
  attn_kernel<<<dim3(1024, 8), 256, 0, stream>>>(qkv, order, attn_o);
  gemm_bt_kernel<1><<<dim3(1024, 2), 256, 0, stream>>>(attn_o, wprojT, b_proj, feat, xres, 256, 256);
  ln_bf16_kernel<<<N_TOK / 4, dim3(64, 4), 0, stream>>>(xres, ln2_g, ln2_b, ln_buf);
  gemm_bt_kernel<2><<<dim3(1024, 8), 256, 0, stream>>>(ln_buf, w1T, b1, nullptr, hbuf, 256, 1024);
  gemm_bt_kernel<3><<<dim3(1024, 2), 256, 0, stream>>>(hbuf, w2T, b2, xres, out, 1024, 256);
}

// Round 2
// 868.316 us; speedup vs baseline: 1.1205x; 1.1205x over previous
//
#include <hip/hip_runtime.h>
#include <hip/hip_bf16.h>

typedef __hip_bfloat16 bf16;
typedef __bf16 bf16x8 __attribute__((ext_vector_type(8)));
typedef float f32x4 __attribute__((ext_vector_type(4)));

#define N_TOK 131072
#define C_DIM 256
#define HID_DIM 1024

// async global->LDS, 16B per lane; lds base must be wave-uniform (dest = base + lane*16)
__device__ __forceinline__ void async_copy16(void* lds, const void* g) {
  __builtin_amdgcn_global_load_lds(
      (const __attribute__((address_space(1))) void*)g,
      (__attribute__((address_space(3))) void*)lds, 16, 0, 0);
}

__device__ __forceinline__ float fast_rcp(float x) {
#if __has_builtin(__builtin_amdgcn_rcpf)
  return __builtin_amdgcn_rcpf(x);  // v_rcp_f32, 1 instr (vs ~12-instr precise div)
#else
  return 1.f / x;
#endif
}

// JAX default gelu (approximate=True, tanh form); tanh(y) = 1 - 2/(e^{2y}+1), inf-safe
__device__ __forceinline__ float fast_gelu(float x) {
  float y = 0.7978845608028654f * x * (1.f + 0.044715f * x * x);
  float e = __expf(2.f * y);
  float th = 1.f - 2.f * fast_rcp(e + 1.f);
  return 0.5f * x * (1.f + th);
}

// LayerNorm over C=256, fp32 in -> bf16 out. block (64,4): one wave per row.
__global__ void ln_bf16_kernel(const float* __restrict__ x,
                               const float* __restrict__ g,
                               const float* __restrict__ b,
                               bf16* __restrict__ out) {
  int row = blockIdx.x * 4 + threadIdx.y;
  int lane = threadIdx.x;
  size_t base = (size_t)row * C_DIM + lane * 4;
  float4 v = *(const float4*)(x + base);
  float s = v.x + v.y + v.z + v.w;
  float s2 = v.x * v.x + v.y * v.y + v.z * v.z + v.w * v.w;
#pragma unroll
  for (int m = 1; m < 64; m <<= 1) { s += __shfl_xor(s, m); s2 += __shfl_xor(s2, m); }
  float mean = s * (1.f / 256.f);
  float var = s2 * (1.f / 256.f) - mean * mean;
  float rstd = rsqrtf(var + 1e-5f);
  float4 gv = *(const float4*)(g + lane * 4);
  float4 bv = *(const float4*)(b + lane * 4);
  union { bf16 h[4]; uint2 u; } pk;
  pk.h[0] = __float2bfloat16((v.x - mean) * rstd * gv.x + bv.x);
  pk.h[1] = __float2bfloat16((v.y - mean) * rstd * gv.y + bv.y);
  pk.h[2] = __float2bfloat16((v.z - mean) * rstd * gv.z + bv.z);
  pk.h[3] = __float2bfloat16((v.w - mean) * rstd * gv.w + bv.w);
  *(uint2*)(out + base) = pk.u;
}

// weight [K,N] fp32 -> [N,K] bf16 (transposed so GEMM reads are K-contiguous)
__global__ void cast_transpose_kernel(const float* __restrict__ in, bf16* __restrict__ out,
                                      int K, int N) {
  int idx = blockIdx.x * 256 + threadIdx.x;
  if (idx >= K * N) return;
  int n = idx / K, k = idx - n * K;
  out[idx] = __float2bfloat16(in[(size_t)k * N + n]);
}

// C[m,n] = sum_k A[m,k]*Bt[n,k] + bias[n] (+ epilogue). 128x128 tile, BK=64,
// 256 thr = 4 waves each 64x64 (4x4 of 16x16x32 MFMA). m97-style global_load_lds staging.
// Grid: x = N-tiles (small, fastest) so an m-tile's A stays L2-resident across n-blocks.
// LDS col-blocks XOR-swizzled by row&7: staging dest stays lane-contiguous (source col
// is swizzled instead), fragment ds_read_b128 becomes bank-uniform.
// EPI: 0 = bf16 out; 1 = fp32 out + res; 2 = gelu -> bf16; 3 = fp32 out + res
template <int EPI>
__global__ __launch_bounds__(256) void gemm_bt_kernel(
    const bf16* __restrict__ A, const bf16* __restrict__ Bt,
    const float* __restrict__ bias, const float* __restrict__ res,
    void* __restrict__ outp, int K, int ldn) {
  __shared__ bf16 sA[128 * 64];
  __shared__ bf16 sB[128 * 64];
  const int tid = threadIdx.x;
  const int wid = tid >> 6;
  const int lane = tid & 63;
  const int quad = lane >> 4;
  const int l16 = lane & 15;
  const int n0 = blockIdx.x * 128;  // N fastest -> A-tile L2 reuse
  const int m0 = blockIdx.y * 128;
  const int wm = (wid >> 1) * 64;
  const int wn = (wid & 1) * 64;
  const int srow = tid >> 3;                       // staging row 0..31 within issue slab
  const int scol = ((tid & 7) ^ (srow & 7)) * 8;   // XOR-swizzled source col block

  // hoisted staging base pointers; bump by 64 elems per K-step
  const bf16* pA = A + (size_t)(m0 + srow) * K + scol;
  const bf16* pB = Bt + (size_t)(n0 + srow) * K + scol;
  const size_t isStride = (size_t)32 * K;

  f32x4 acc[4][4] = {};

  for (int k0 = 0; k0 < K; k0 += 64) {
#pragma unroll
    for (int is = 0; is < 4; ++is) {
      async_copy16(&sA[is * 2048 + wid * 512], pA + is * isStride);
      async_copy16(&sB[is * 2048 + wid * 512], pB + is * isStride);
    }
    pA += 64;
    pB += 64;
    __syncthreads();  // drains vmcnt: staged tiles visible
#pragma unroll
    for (int kk = 0; kk < 64; kk += 32) {
      bf16x8 af[4], bfr[4];
#pragma unroll
      for (int i = 0; i < 4; ++i)
        af[i] = *(const bf16x8*)&sA[(wm + i * 16 + l16) * 64 +
                                    ((((kk >> 3) + quad) ^ (l16 & 7)) << 3)];
#pragma unroll
      for (int j = 0; j < 4; ++j)
        bfr[j] = *(const bf16x8*)&sB[(wn + j * 16 + l16) * 64 +
                                     ((((kk >> 3) + quad) ^ (l16 & 7)) << 3)];
#pragma unroll
      for (int i = 0; i < 4; ++i)
#pragma unroll
        for (int j = 0; j < 4; ++j)
          acc[i][j] = __builtin_amdgcn_mfma_f32_16x16x32_bf16(af[i], bfr[j], acc[i][j], 0, 0, 0);
    }
    __syncthreads();  // protect LDS before next staging
  }

  // epilogue: bias preloaded, row offset computed once per 4 stores
  float bv[4];
#pragma unroll
  for (int j = 0; j < 4; ++j) bv[j] = bias[n0 + wn + j * 16 + l16];
  const int colb = n0 + wn + l16;
#pragma unroll
  for (int i = 0; i < 4; ++i) {
    int rowb = m0 + wm + i * 16 + quad * 4;  // C/D layout: row = quad*4+reg
#pragma unroll
    for (int r = 0; r < 4; ++r) {
      size_t rowoff = (size_t)(rowb + r) * ldn + colb;
#pragma unroll
      for (int j = 0; j < 4; ++j) {
        size_t idx = rowoff + j * 16;
        float v = acc[i][j][r] + bv[j];
        if constexpr (EPI == 0) {
          ((bf16*)outp)[idx] = __float2bfloat16(v);
        } else if constexpr (EPI == 1) {
          ((float*)outp)[idx] = v + res[idx];
        } else if constexpr (EPI == 2) {
          ((bf16*)outp)[idx] = __float2bfloat16(fast_gelu(v));
        } else {
          ((float*)outp)[idx] = v + res[idx];
        }
      }
    }
  }
}

// one block per (head h, window p) -- h fastest so a window's qkv rows are read once
// into L2 and reused by all 8 heads. qkv row: [0,256)=q, [256,512)=k, [512,768)=v.
__global__ __launch_bounds__(256) void attn_kernel(
    const bf16* __restrict__ qkv, const int* __restrict__ order,
    bf16* __restrict__ outw) {
  __shared__ bf16 sK[128 * 40];    // K rows, +8 pad
  __shared__ bf16 sVt[32 * 136];   // V transposed [d][k], +8 pad
  __shared__ bf16 sP[128 * 136];   // softmax probs, +8 pad
  __shared__ int sOrd[128];
  const int h = blockIdx.x;
  const int p = blockIdx.y;
  const int tid = threadIdx.x;
  const int wid = tid >> 6;
  const int lane = tid & 63;
  const int quad = lane >> 4;
  const int l16 = lane & 15;

  if (tid < 128) sOrd[tid] = order[p * 128 + tid];
  __syncthreads();

  {  // stage K rows and V^T
    int r = tid >> 1;
    int half = (tid & 1) * 16;
    size_t base = (size_t)sOrd[r] * 768 + h * 32;
    uint4 ka = *(const uint4*)&qkv[base + 256 + half];
    uint4 kb = *(const uint4*)&qkv[base + 256 + half + 8];
    *(uint4*)&sK[r * 40 + half] = ka;
    *(uint4*)&sK[r * 40 + half + 8] = kb;
    union { uint4 u[2]; bf16 e[16]; } vv;
    vv.u[0] = *(const uint4*)&qkv[base + 512 + half];
    vv.u[1] = *(const uint4*)&qkv[base + 512 + half + 8];
#pragma unroll
    for (int c = 0; c < 16; ++c) sVt[(half + c) * 136 + r] = vv.e[c];
  }
  __syncthreads();

  // Q fragments straight from global: A-frag = Q[m = l16][k = quad*8+j], D=32 = one K-step
  bf16x8 qf[2];
#pragma unroll
  for (int t = 0; t < 2; ++t) {
    int r = wid * 32 + t * 16 + l16;
    qf[t] = *(const bf16x8*)&qkv[(size_t)sOrd[r] * 768 + h * 32 + quad * 8];
  }

  const f32x4 zero = {0.f, 0.f, 0.f, 0.f};
  f32x4 s[2][8];  // wave owns 32 q-rows x 128 keys
#pragma unroll
  for (int ct = 0; ct < 8; ++ct) {
    bf16x8 kf = *(const bf16x8*)&sK[(ct * 16 + l16) * 40 + quad * 8];  // B[k=d][n=key]
#pragma unroll
    for (int t = 0; t < 2; ++t)
      s[t][ct] = __builtin_amdgcn_mfma_f32_16x16x32_bf16(qf[t], kf, zero, 0, 0, 0);
  }

  const float scale = 0.17677669529663687f;  // 1/sqrt(32)
#pragma unroll
  for (int t = 0; t < 2; ++t) {
#pragma unroll
    for (int r = 0; r < 4; ++r) {  // row = wid*32 + t*16 + quad*4 + r, cols in 16-lane quad
      float mx = -1e30f;
#pragma unroll
      for (int ct = 0; ct < 8; ++ct) mx = fmaxf(mx, s[t][ct][r]);
      mx *= scale;
#pragma unroll
      for (int mk = 1; mk < 16; mk <<= 1) mx = fmaxf(mx, __shfl_xor(mx, mk));
      float sum = 0.f;
#pragma unroll
      for (int ct = 0; ct < 8; ++ct) {
        float e = __expf(scale * s[t][ct][r] - mx);
        s[t][ct][r] = e;
        sum += e;
      }
#pragma unroll
      for (int mk = 1; mk < 16; mk <<= 1) sum += __shfl_xor(sum, mk);
      float inv = fast_rcp(sum);
      int prow = wid * 32 + t * 16 + quad * 4 + r;
#pragma unroll
      for (int ct = 0; ct < 8; ++ct)
        sP[prow * 136 + ct * 16 + l16] = __float2bfloat16(s[t][ct][r] * inv);
    }
  }
  __syncthreads();  // P C-layout -> A-layout round trip through LDS

  f32x4 o[2][2] = {};
#pragma unroll
  for (int ks = 0; ks < 4; ++ks) {
    bf16x8 vf[2];
#pragma unroll
    for (int n = 0; n < 2; ++n)  // B[k][n=d]: read V^T[d][k] contiguously
      vf[n] = *(const bf16x8*)&sVt[(n * 16 + l16) * 136 + ks * 32 + quad * 8];
#pragma unroll
    for (int t = 0; t < 2; ++t) {
      bf16x8 pf = *(const bf16x8*)&sP[(wid * 32 + t * 16 + l16) * 136 + ks * 32 + quad * 8];
#pragma unroll
      for (int n = 0; n < 2; ++n)
        o[t][n] = __builtin_amdgcn_mfma_f32_16x16x32_bf16(pf, vf[n], o[t][n], 0, 0, 0);
    }
  }

#pragma unroll
  for (int t = 0; t < 2; ++t) {
    int rowb = wid * 32 + t * 16 + quad * 4;
#pragma unroll
    for (int r = 0; r < 4; ++r) {
      size_t gbase = (size_t)sOrd[rowb + r] * 256 + h * 32;  // scatter == out[inverse]
#pragma unroll
      for (int n = 0; n < 2; ++n)
        outw[gbase + n * 16 + l16] = __float2bfloat16(o[t][n][r]);
    }
  }
}

extern "C" void kernel_launch(void* const* d_in, const int* in_sizes, int n_in,
                              void* d_out, int out_size, void* d_ws, size_t ws_size,
                              hipStream_t stream) {
  const float* feat   = (const float*)d_in[0];
  const float* ln1_g  = (const float*)d_in[1];
  const float* ln1_b  = (const float*)d_in[2];
  const float* w_qkv  = (const float*)d_in[3];
  const float* b_qkv  = (const float*)d_in[4];
  const float* w_proj = (const float*)d_in[5];
  const float* b_proj = (const float*)d_in[6];
  const float* ln2_g  = (const float*)d_in[7];
  const float* ln2_b  = (const float*)d_in[8];
  const float* w1     = (const float*)d_in[9];
  const float* b1     = (const float*)d_in[10];
  const float* w2     = (const float*)d_in[11];
  const float* b2     = (const float*)d_in[12];
  const int* order    = (const int*)d_in[13];
  float* out = (float*)d_out;

  char* ws = (char*)d_ws;
  size_t off = 0;
  auto take = [&](size_t bytes) {
    char* pp = ws + off;
    off += (bytes + 255) & ~(size_t)255;
    return pp;
  };
  bf16* ln_buf  = (bf16*)take((size_t)N_TOK * 256 * 2);   // ln1, later reused for ln2
  bf16* qkv     = (bf16*)take((size_t)N_TOK * 768 * 2);
  bf16* attn_o  = (bf16*)take((size_t)N_TOK * 256 * 2);
  float* xres   = (float*)take((size_t)N_TOK * 256 * 4);
  bf16* wqkvT   = (bf16*)take(768 * 256 * 2);
  bf16* wprojT  = (bf16*)take(256 * 256 * 2);
  bf16* w1T     = (bf16*)take(1024 * 256 * 2);
  bf16* w2T     = (bf16*)take(256 * 1024 * 2);
  bf16* hbuf    = qkv;  // h (N*1024*2 B) exactly overlays dead qkv+attn_o region

  cast_transpose_kernel<<<768, 256, 0, stream>>>(w_qkv, wqkvT, 256, 768);
  cast_transpose_kernel<<<256, 256, 0, stream>>>(w_proj, wprojT, 256, 256);
  cast_transpose_kernel<<<1024, 256, 0, stream>>>(w1, w1T, 256, 1024);
  cast_transpose_kernel<<<1024, 256, 0, stream>>>(w2, w2T, 1024, 256);

  ln_bf16_kernel<<<N_TOK / 4, dim3(64, 4), 0, stream>>>(feat, ln1_g, ln1_b, ln_buf);
  gemm_bt_kernel<0><<<dim3(6, 1024), 256, 0, stream>>>(ln_buf, wqkvT, b_qkv, nullptr, qkv, 256, 768);
  attn_kernel<<<dim3(8, 1024), 256, 0, stream>>>(qkv, order, attn_o);
  gemm_bt_kernel<1><<<dim3(2, 1024), 256, 0, stream>>>(attn_o, wprojT, b_proj, feat, xres, 256, 256);
  ln_bf16_kernel<<<N_TOK / 4, dim3(64, 4), 0, stream>>>(xres, ln2_g, ln2_b, ln_buf);
  gemm_bt_kernel<2><<<dim3(8, 1024), 256, 0, stream>>>(ln_buf, w1T, b1, nullptr, hbuf, 256, 1024);
  gemm_bt_kernel<3><<<dim3(2, 1024), 256, 0, stream>>>(hbuf, w2T, b2, xres, out, 1024, 256);
}

// Round 3
// 832.582 us; speedup vs baseline: 1.1685x; 1.0429x over previous
//
#include <hip/hip_runtime.h>
#include <hip/hip_bf16.h>

typedef __hip_bfloat16 bf16;
typedef __bf16 bf16x8 __attribute__((ext_vector_type(8)));
typedef float f32x4 __attribute__((ext_vector_type(4)));

#define N_TOK 131072
#define C_DIM 256
#define HID_DIM 1024

// async global->LDS, 16B per lane; lds base must be wave-uniform (dest = base + lane*16)
__device__ __forceinline__ void async_copy16(void* lds, const void* g) {
  __builtin_amdgcn_global_load_lds(
      (const __attribute__((address_space(1))) void*)g,
      (__attribute__((address_space(3))) void*)lds, 16, 0, 0);
}

__device__ __forceinline__ float fast_rcp(float x) {
#if __has_builtin(__builtin_amdgcn_rcpf)
  return __builtin_amdgcn_rcpf(x);  // v_rcp_f32, 1 instr
#else
  return 1.f / x;
#endif
}

// RNE float->bf16 in 3 VALU ops (valid for all finite values; no NaNs in this net)
__device__ __forceinline__ bf16 bf16_rne(float f) {
  unsigned u = __float_as_uint(f);
  u += 0x7FFF + ((u >> 16) & 1);
  unsigned short s = (unsigned short)(u >> 16);
  return *reinterpret_cast<bf16*>(&s);
}

// gelu tanh-approx via exact identity 0.5x(1+tanh(y)) = x*sigmoid(2y):
// z = 1.595769122*x + 0.071354816*x^3; gelu = x / (1 + e^-z). ~7 VALU incl exp/rcp.
__device__ __forceinline__ float fast_gelu(float x) {
  float t = x * x;
  float u = __builtin_fmaf(0.07135481627f, t, 1.5957691216f);
  float z = x * u;
  float e = __expf(-z);
  return x * fast_rcp(1.f + e);
}

// LayerNorm over C=256, fp32 in -> bf16 out. block (64,4): one wave per row.
__global__ void ln_bf16_kernel(const float* __restrict__ x,
                               const float* __restrict__ g,
                               const float* __restrict__ b,
                               bf16* __restrict__ out) {
  int row = blockIdx.x * 4 + threadIdx.y;
  int lane = threadIdx.x;
  size_t base = (size_t)row * C_DIM + lane * 4;
  float4 v = *(const float4*)(x + base);
  float s = v.x + v.y + v.z + v.w;
  float s2 = v.x * v.x + v.y * v.y + v.z * v.z + v.w * v.w;
#pragma unroll
  for (int m = 1; m < 64; m <<= 1) { s += __shfl_xor(s, m); s2 += __shfl_xor(s2, m); }
  float mean = s * (1.f / 256.f);
  float var = s2 * (1.f / 256.f) - mean * mean;
  float rstd = rsqrtf(var + 1e-5f);
  float4 gv = *(const float4*)(g + lane * 4);
  float4 bv = *(const float4*)(b + lane * 4);
  union { bf16 h[4]; uint2 u; } pk;
  pk.h[0] = bf16_rne((v.x - mean) * rstd * gv.x + bv.x);
  pk.h[1] = bf16_rne((v.y - mean) * rstd * gv.y + bv.y);
  pk.h[2] = bf16_rne((v.z - mean) * rstd * gv.z + bv.z);
  pk.h[3] = bf16_rne((v.w - mean) * rstd * gv.w + bv.w);
  *(uint2*)(out + base) = pk.u;
}

// weight [K,N] fp32 -> [N,K] bf16 (transposed so GEMM reads are K-contiguous)
__global__ void cast_transpose_kernel(const float* __restrict__ in, bf16* __restrict__ out,
                                      int K, int N) {
  int idx = blockIdx.x * 256 + threadIdx.x;
  if (idx >= K * N) return;
  int n = idx / K, k = idx - n * K;
  out[idx] = bf16_rne(in[(size_t)k * N + n]);
}

// C[m,n] = sum_k A[m,k]*Bt[n,k] + bias[n] (+ epilogue). 128x128 tile, BK=64,
// 256 thr = 4 waves each 64x64 (4x4 of 16x16x32 MFMA). m97-style global_load_lds staging.
// XCD-aware bid decode: XCD x (= bid&7) iterates ALL NXT n-tiles of one m-tile
// consecutively, so the A m-tile (64 KB) stays resident in that XCD's private L2.
// LDS col-blocks XOR-swizzled by row&7 (source-side swizzle keeps the wave-uniform
// global_load_lds dest); fragment ds_read_b128 measured conflict-free.
// EPI: 0 = bf16 out; 1 = fp32 out + res; 2 = gelu -> bf16; 3 = fp32 out + res
template <int EPI, int NXT>
__global__ __launch_bounds__(256) void gemm_bt_kernel(
    const bf16* __restrict__ A, const bf16* __restrict__ Bt,
    const float* __restrict__ bias, const float* __restrict__ res,
    void* __restrict__ outp, int K, int ldn) {
  __shared__ bf16 sA[128 * 64];
  __shared__ bf16 sB[128 * 64];
  const int bid = blockIdx.x;
  const int xcd = bid & 7;
  const int j = bid >> 3;
  const int n0 = (j % NXT) * 128;
  const int m0 = ((j / NXT) * 8 + xcd) * 128;
  const int tid = threadIdx.x;
  const int wid = tid >> 6;
  const int lane = tid & 63;
  const int quad = lane >> 4;
  const int l16 = lane & 15;
  const int wm = (wid >> 1) * 64;
  const int wn = (wid & 1) * 64;
  const int srow = tid >> 3;                       // staging row 0..31 within issue slab
  const int scol = ((tid & 7) ^ (srow & 7)) * 8;   // XOR-swizzled source col block

  const bf16* pA = A + (size_t)(m0 + srow) * K + scol;
  const bf16* pB = Bt + (size_t)(n0 + srow) * K + scol;
  const size_t isStride = (size_t)32 * K;

  f32x4 acc[4][4] = {};

  for (int k0 = 0; k0 < K; k0 += 64) {
#pragma unroll
    for (int is = 0; is < 4; ++is) {
      async_copy16(&sA[is * 2048 + wid * 512], pA + is * isStride);
      async_copy16(&sB[is * 2048 + wid * 512], pB + is * isStride);
    }
    pA += 64;
    pB += 64;
    __syncthreads();  // drains vmcnt: staged tiles visible
#pragma unroll
    for (int kk = 0; kk < 64; kk += 32) {
      bf16x8 af[4], bfr[4];
#pragma unroll
      for (int i = 0; i < 4; ++i)
        af[i] = *(const bf16x8*)&sA[(wm + i * 16 + l16) * 64 +
                                    ((((kk >> 3) + quad) ^ (l16 & 7)) << 3)];
#pragma unroll
      for (int j2 = 0; j2 < 4; ++j2)
        bfr[j2] = *(const bf16x8*)&sB[(wn + j2 * 16 + l16) * 64 +
                                      ((((kk >> 3) + quad) ^ (l16 & 7)) << 3)];
#pragma unroll
      for (int i = 0; i < 4; ++i)
#pragma unroll
        for (int j2 = 0; j2 < 4; ++j2)
          acc[i][j2] = __builtin_amdgcn_mfma_f32_16x16x32_bf16(af[i], bfr[j2], acc[i][j2], 0, 0, 0);
    }
    __syncthreads();  // protect LDS before next staging
  }

  // epilogue: bias preloaded, row offset computed once per 4 stores
  float bv[4];
#pragma unroll
  for (int j2 = 0; j2 < 4; ++j2) bv[j2] = bias[n0 + wn + j2 * 16 + l16];
  const int colb = n0 + wn + l16;
#pragma unroll
  for (int i = 0; i < 4; ++i) {
    int rowb = m0 + wm + i * 16 + quad * 4;  // C/D layout: row = quad*4+reg
#pragma unroll
    for (int r = 0; r < 4; ++r) {
      size_t rowoff = (size_t)(rowb + r) * ldn + colb;
#pragma unroll
      for (int j2 = 0; j2 < 4; ++j2) {
        size_t idx = rowoff + j2 * 16;
        float v = acc[i][j2][r] + bv[j2];
        if constexpr (EPI == 0) {
          ((bf16*)outp)[idx] = bf16_rne(v);
        } else if constexpr (EPI == 1) {
          ((float*)outp)[idx] = v + res[idx];
        } else if constexpr (EPI == 2) {
          ((bf16*)outp)[idx] = bf16_rne(fast_gelu(v));
        } else {
          ((float*)outp)[idx] = v + res[idx];
        }
      }
    }
  }
}

// one block per (window p, head h). XCD-aware decode: one window's 8 heads all land
// on the same XCD so the window's gathered qkv rows are fetched into that L2 once.
__global__ __launch_bounds__(256) void attn_kernel(
    const bf16* __restrict__ qkv, const int* __restrict__ order,
    bf16* __restrict__ outw) {
  __shared__ bf16 sK[128 * 40];    // K rows, +8 pad
  __shared__ bf16 sVt[32 * 136];   // V transposed [d][k], +8 pad
  __shared__ bf16 sP[128 * 136];   // softmax probs, +8 pad
  __shared__ int sOrd[128];
  const int bid = blockIdx.x;
  const int h = (bid >> 3) & 7;
  const int p = ((bid >> 6) << 3) | (bid & 7);
  const int tid = threadIdx.x;
  const int wid = tid >> 6;
  const int lane = tid & 63;
  const int quad = lane >> 4;
  const int l16 = lane & 15;

  if (tid < 128) sOrd[tid] = order[p * 128 + tid];
  __syncthreads();

  {  // stage K rows and V^T
    int r = tid >> 1;
    int half = (tid & 1) * 16;
    size_t base = (size_t)sOrd[r] * 768 + h * 32;
    uint4 ka = *(const uint4*)&qkv[base + 256 + half];
    uint4 kb = *(const uint4*)&qkv[base + 256 + half + 8];
    *(uint4*)&sK[r * 40 + half] = ka;
    *(uint4*)&sK[r * 40 + half + 8] = kb;
    union { uint4 u[2]; bf16 e[16]; } vv;
    vv.u[0] = *(const uint4*)&qkv[base + 512 + half];
    vv.u[1] = *(const uint4*)&qkv[base + 512 + half + 8];
#pragma unroll
    for (int c = 0; c < 16; ++c) sVt[(half + c) * 136 + r] = vv.e[c];
  }
  __syncthreads();

  // Q fragments straight from global: A-frag = Q[m = l16][k = quad*8+j], D=32 = one K-step
  bf16x8 qf[2];
#pragma unroll
  for (int t = 0; t < 2; ++t) {
    int r = wid * 32 + t * 16 + l16;
    qf[t] = *(const bf16x8*)&qkv[(size_t)sOrd[r] * 768 + h * 32 + quad * 8];
  }

  const f32x4 zero = {0.f, 0.f, 0.f, 0.f};
  f32x4 s[2][8];  // wave owns 32 q-rows x 128 keys
#pragma unroll
  for (int ct = 0; ct < 8; ++ct) {
    bf16x8 kf = *(const bf16x8*)&sK[(ct * 16 + l16) * 40 + quad * 8];  // B[k=d][n=key]
#pragma unroll
    for (int t = 0; t < 2; ++t)
      s[t][ct] = __builtin_amdgcn_mfma_f32_16x16x32_bf16(qf[t], kf, zero, 0, 0, 0);
  }

  const float scale = 0.17677669529663687f;  // 1/sqrt(32)
#pragma unroll
  for (int t = 0; t < 2; ++t) {
#pragma unroll
    for (int r = 0; r < 4; ++r) {  // row = wid*32 + t*16 + quad*4 + r, cols in 16-lane quad
      float mx = -1e30f;
#pragma unroll
      for (int ct = 0; ct < 8; ++ct) mx = fmaxf(mx, s[t][ct][r]);
      mx *= scale;
#pragma unroll
      for (int mk = 1; mk < 16; mk <<= 1) mx = fmaxf(mx, __shfl_xor(mx, mk));
      float sum = 0.f;
#pragma unroll
      for (int ct = 0; ct < 8; ++ct) {
        float e = __expf(scale * s[t][ct][r] - mx);
        s[t][ct][r] = e;
        sum += e;
      }
#pragma unroll
      for (int mk = 1; mk < 16; mk <<= 1) sum += __shfl_xor(sum, mk);
      float inv = fast_rcp(sum);
      int prow = wid * 32 + t * 16 + quad * 4 + r;
#pragma unroll
      for (int ct = 0; ct < 8; ++ct)
        sP[prow * 136 + ct * 16 + l16] = bf16_rne(s[t][ct][r] * inv);
    }
  }
  __syncthreads();  // P C-layout -> A-layout round trip through LDS

  f32x4 o[2][2] = {};
#pragma unroll
  for (int ks = 0; ks < 4; ++ks) {
    bf16x8 vf[2];
#pragma unroll
    for (int n = 0; n < 2; ++n)  // B[k][n=d]: read V^T[d][k] contiguously
      vf[n] = *(const bf16x8*)&sVt[(n * 16 + l16) * 136 + ks * 32 + quad * 8];
#pragma unroll
    for (int t = 0; t < 2; ++t) {
      bf16x8 pf = *(const bf16x8*)&sP[(wid * 32 + t * 16 + l16) * 136 + ks * 32 + quad * 8];
#pragma unroll
      for (int n = 0; n < 2; ++n)
        o[t][n] = __builtin_amdgcn_mfma_f32_16x16x32_bf16(pf, vf[n], o[t][n], 0, 0, 0);
    }
  }

#pragma unroll
  for (int t = 0; t < 2; ++t) {
    int rowb = wid * 32 + t * 16 + quad * 4;
#pragma unroll
    for (int r = 0; r < 4; ++r) {
      size_t gbase = (size_t)sOrd[rowb + r] * 256 + h * 32;  // scatter == out[inverse]
#pragma unroll
      for (int n = 0; n < 2; ++n)
        outw[gbase + n * 16 + l16] = bf16_rne(o[t][n][r]);
    }
  }
}

extern "C" void kernel_launch(void* const* d_in, const int* in_sizes, int n_in,
                              void* d_out, int out_size, void* d_ws, size_t ws_size,
                              hipStream_t stream) {
  const float* feat   = (const float*)d_in[0];
  const float* ln1_g  = (const float*)d_in[1];
  const float* ln1_b  = (const float*)d_in[2];
  const float* w_qkv  = (const float*)d_in[3];
  const float* b_qkv  = (const float*)d_in[4];
  const float* w_proj = (const float*)d_in[5];
  const float* b_proj = (const float*)d_in[6];
  const float* ln2_g  = (const float*)d_in[7];
  const float* ln2_b  = (const float*)d_in[8];
  const float* w1     = (const float*)d_in[9];
  const float* b1     = (const float*)d_in[10];
  const float* w2     = (const float*)d_in[11];
  const float* b2     = (const float*)d_in[12];
  const int* order    = (const int*)d_in[13];
  float* out = (float*)d_out;

  char* ws = (char*)d_ws;
  size_t off = 0;
  auto take = [&](size_t bytes) {
    char* pp = ws + off;
    off += (bytes + 255) & ~(size_t)255;
    return pp;
  };
  bf16* ln_buf  = (bf16*)take((size_t)N_TOK * 256 * 2);   // ln1, later reused for ln2
  bf16* qkv     = (bf16*)take((size_t)N_TOK * 768 * 2);
  bf16* attn_o  = (bf16*)take((size_t)N_TOK * 256 * 2);
  float* xres   = (float*)take((size_t)N_TOK * 256 * 4);
  bf16* wqkvT   = (bf16*)take(768 * 256 * 2);
  bf16* wprojT  = (bf16*)take(256 * 256 * 2);
  bf16* w1T     = (bf16*)take(1024 * 256 * 2);
  bf16* w2T     = (bf16*)take(256 * 1024 * 2);
  bf16* hbuf    = qkv;  // h (N*1024*2 B) exactly overlays dead qkv+attn_o region

  cast_transpose_kernel<<<768, 256, 0, stream>>>(w_qkv, wqkvT, 256, 768);
  cast_transpose_kernel<<<256, 256, 0, stream>>>(w_proj, wprojT, 256, 256);
  cast_transpose_kernel<<<1024, 256, 0, stream>>>(w1, w1T, 256, 1024);
  cast_transpose_kernel<<<1024, 256, 0, stream>>>(w2, w2T, 1024, 256);

  ln_bf16_kernel<<<N_TOK / 4, dim3(64, 4), 0, stream>>>(feat, ln1_g, ln1_b, ln_buf);
  gemm_bt_kernel<0, 6><<<6 * 1024, 256, 0, stream>>>(ln_buf, wqkvT, b_qkv, nullptr, qkv, 256, 768);
  attn_kernel<<<8 * 1024, 256, 0, stream>>>(qkv, order, attn_o);
  gemm_bt_kernel<1, 2><<<2 * 1024, 256, 0, stream>>>(attn_o, wprojT, b_proj, feat, xres, 256, 256);
  ln_bf16_kernel<<<N_TOK / 4, dim3(64, 4), 0, stream>>>(xres, ln2_g, ln2_b, ln_buf);
  gemm_bt_kernel<2, 8><<<8 * 1024, 256, 0, stream>>>(ln_buf, w1T, b1, nullptr, hbuf, 256, 1024);
  gemm_bt_kernel<3, 2><<<2 * 1024, 256, 0, stream>>>(hbuf, w2T, b2, xres, out, 1024, 256);
}